// Round 9
// baseline (280.949 us; speedup 1.0000x reference)
//
#include <hip/hip_runtime.h>
#include <hip/hip_bf16.h>

#define BQ 4
#define QN 8192
#define DD 256
#define LL 2
#define H0c 128
#define W0c 128
#define H1c 64
#define W1c 64
#define EPSF 1e-5f

typedef unsigned short ushort_t;
typedef __attribute__((ext_vector_type(8))) short short8;
typedef __attribute__((ext_vector_type(8))) unsigned short ushortx8;
typedef __attribute__((ext_vector_type(4))) unsigned short ushortx4;
typedef __attribute__((ext_vector_type(4))) float floatx4;
typedef __attribute__((ext_vector_type(4))) _Float16 half4;

static __device__ __forceinline__ unsigned short f2bf(float f) {
    __hip_bfloat16 h = __float2bfloat16(f);
    return __builtin_bit_cast(unsigned short, h);
}
static __device__ __forceinline__ unsigned short f2h(float f) {
    _Float16 h = (_Float16)f;
    return __builtin_bit_cast(unsigned short, h);
}
// fp16 halves of a u32 -> f32 (backend can fuse fpext into v_fma_mix_f32 at the FMA site)
static __device__ __forceinline__ float h_lo(unsigned int u) {
    _Float16 h = __builtin_bit_cast(_Float16, (unsigned short)(u & 0xffffu));
    return (float)h;
}
static __device__ __forceinline__ float h_hi(unsigned int u) {
    _Float16 h = __builtin_bit_cast(_Float16, (unsigned short)(u >> 16));
    return (float)h;
}

// ---------------- Kernel 1: prep — standalone transposes + weight pack (verified) ----------------
#define PT0 4096
#define PT1 1024
#define PTW 16
__global__ __launch_bounds__(256) void prep(const float* __restrict__ map0, const float* __restrict__ map1,
                                            const float* __restrict__ Wout,
                                            const float* __restrict__ Wrd, const float* __restrict__ brd,
                                            const float* __restrict__ Woff, const float* __restrict__ boff,
                                            const float* __restrict__ Wattn, const float* __restrict__ battn,
                                            ushort_t* __restrict__ mapT0, ushort_t* __restrict__ mapT1,
                                            __hip_bfloat16* __restrict__ WoutT,
                                            float* __restrict__ Wall, float* __restrict__ bias64) {
    __shared__ float tile[64][65];   // [ch_local][hw_local], 16.6 KB
    int blk = blockIdx.x;
    int tid = threadIdx.x;
    const float* in; ushort_t* outp; int HW, b, c0, hw0; bool tohalf;
    if (blk < PT0) {
        int l = blk; b = l >> 10; int r = l & 1023;
        c0 = (r >> 8) << 6; hw0 = (r & 255) << 6;
        in = map0; outp = mapT0; HW = H0c * W0c; tohalf = true;
    } else if (blk < PT0 + PT1) {
        int l = blk - PT0; b = l >> 8; int r = l & 255;
        c0 = (r >> 6) << 6; hw0 = (r & 63) << 6;
        in = map1; outp = mapT1; HW = H1c * W1c; tohalf = true;
    } else if (blk < PT0 + PT1 + PTW) {
        int l = blk - PT0 - PT1; b = 0;
        c0 = (l >> 2) << 6; hw0 = (l & 3) << 6;
        in = Wout; outp = (ushort_t*)WoutT; HW = DD; tohalf = false;
    } else {
        int l = blk - PT0 - PT1 - PTW;
        int idx = l * 256 + tid;               // 0..16383
        int k = idx >> 6, c = idx & 63;
        float v = (c < 4)  ? Wrd[k * 4 + c]
                : (c < 36) ? Woff[k * 32 + (c - 4)]
                : (c < 52) ? Wattn[k * 16 + (c - 36)]
                : 0.f;
        Wall[idx] = v;
        if (idx < 64) {
            float bv = (idx < 4)  ? brd[idx]
                     : (idx < 36) ? boff[idx - 4]
                     : (idx < 52) ? battn[idx - 36]
                     : 0.f;
            bias64[idx] = bv;
        }
        return;
    }
    const float* inb = in + (size_t)b * DD * HW + (size_t)c0 * HW + hw0;
    ushort_t* outb = outp + (size_t)b * DD * HW + (size_t)hw0 * DD + c0;

    int row = tid >> 2;             // 0..63 channel-local
    int q16 = (tid & 3) * 16;       // col base
#pragma unroll
    for (int j = 0; j < 4; j++) {
        float4 v = *(const float4*)(inb + (size_t)row * HW + q16 + j * 4);
        tile[row][q16 + j * 4 + 0] = v.x;
        tile[row][q16 + j * 4 + 1] = v.y;
        tile[row][q16 + j * 4 + 2] = v.z;
        tile[row][q16 + j * 4 + 3] = v.w;
    }
    __syncthreads();

    int hwr = tid >> 4;             // 0..15
    int c4 = (tid & 15) * 4;        // 0..60
#pragma unroll
    for (int jj = 0; jj < 4; jj++) {
        int rr = hwr + jj * 16;     // hw row 0..63
        ushortx4 o;
        if (tohalf) {
            o[0] = f2h(tile[c4 + 0][rr]);
            o[1] = f2h(tile[c4 + 1][rr]);
            o[2] = f2h(tile[c4 + 2][rr]);
            o[3] = f2h(tile[c4 + 3][rr]);
        } else {
            o[0] = f2bf(tile[c4 + 0][rr]);
            o[1] = f2bf(tile[c4 + 1][rr]);
            o[2] = f2bf(tile[c4 + 2][rr]);
            o[3] = f2bf(tile[c4 + 3][rr]);
        }
        *(ushortx4*)(outb + (size_t)rr * DD + c4) = o;
    }
}

// ---------------- Kernel 2: proj GEMM (fp32) + fused sampling-descriptor epilogue (verified) ----------------
__global__ __launch_bounds__(256) void proj_desc(const float* __restrict__ q,
                                                 const float* __restrict__ Wall,
                                                 const float* __restrict__ bias64,
                                                 const float* __restrict__ base_ref,
                                                 int2* __restrict__ dsi,
                                                 half4* __restrict__ dsw) {
    __shared__ float As[32][68];
    __shared__ float Bs[32][64];
    __shared__ float prs[64][68];
    int tid = threadIdx.x;
    int tx = tid & 15, ty = tid >> 4;
    int m0 = blockIdx.x * 64;
    float acc[4][4] = {};

    for (int kt = 0; kt < DD; kt += 32) {
#pragma unroll
        for (int j = 0; j < 8; j++) {
            int e = tid + 256 * j;
            int r = e >> 5, k = e & 31;
            As[k][r] = q[(size_t)(m0 + r) * DD + kt + k];
        }
#pragma unroll
        for (int j = 0; j < 8; j++) {
            int e = tid + 256 * j;
            int k = e >> 6, nn = e & 63;
            Bs[k][nn] = Wall[(size_t)(kt + k) * 64 + nn];
        }
        __syncthreads();
#pragma unroll
        for (int k = 0; k < 32; k++) {
            const float4 a4 = *(const float4*)&As[k][ty * 4];
            const float4 b4 = *(const float4*)&Bs[k][tx * 4];
            acc[0][0] += a4.x * b4.x; acc[0][1] += a4.x * b4.y; acc[0][2] += a4.x * b4.z; acc[0][3] += a4.x * b4.w;
            acc[1][0] += a4.y * b4.x; acc[1][1] += a4.y * b4.y; acc[1][2] += a4.y * b4.z; acc[1][3] += a4.y * b4.w;
            acc[2][0] += a4.z * b4.x; acc[2][1] += a4.z * b4.y; acc[2][2] += a4.z * b4.z; acc[2][3] += a4.z * b4.w;
            acc[3][0] += a4.w * b4.x; acc[3][1] += a4.w * b4.y; acc[3][2] += a4.w * b4.z; acc[3][3] += a4.w * b4.w;
        }
        __syncthreads();
    }

    float4 bias = *(const float4*)&bias64[tx * 4];
#pragma unroll
    for (int i = 0; i < 4; i++) {
        float4 v;
        v.x = acc[i][0] + bias.x;
        v.y = acc[i][1] + bias.y;
        v.z = acc[i][2] + bias.z;
        v.w = acc[i][3] + bias.w;
        *(float4*)&prs[ty * 4 + i][tx * 4] = v;
    }
    __syncthreads();

    int ql = tid >> 2, sq = tid & 3;
    int n = m0 + ql, b = n >> 13;        // QN = 8192
    const float* p = prs[ql];

    float mx = p[36];
#pragma unroll
    for (int i = 1; i < 16; i++) mx = fmaxf(mx, p[36 + i]);
    float sum = 0.f;
#pragma unroll
    for (int i = 0; i < 16; i++) sum += __expf(p[36 + i] - mx);
    float inv = 1.f / sum;

#pragma unroll
    for (int u = 0; u < 4; u++) {
        int s = sq * 4 + u;
        int l = s >> 3;
        float a = __expf(p[36 + s] - mx) * inv;

        int W = l ? W1c : W0c;
        int H = l ? H1c : H0c;
        float Wf = (float)W, Hf = (float)H;

        float bx = base_ref[(b * LL + l) * 2 + 0];
        float by = base_ref[(b * LL + l) * 2 + 1];
        bx = fminf(fmaxf(bx, EPSF), 1.f - EPSF);
        by = fminf(fmaxf(by, EPSF), 1.f - EPSF);
        float lgx = logf(bx / (1.f - bx));
        float lgy = logf(by / (1.f - by));
        float refx = 1.f / (1.f + __expf(-(lgx + p[l * 2 + 0])));
        float refy = 1.f / (1.f + __expf(-(lgy + p[l * 2 + 1])));

        float locx = refx + p[4 + s * 2 + 0] / Wf;
        float locy = refy + p[4 + s * 2 + 1] / Hf;
        if (l == 1) locy = locy - floorf(locy);   // jnp.remainder(y, 1.0)

        float gx = locx * 2.f - 1.f;
        float gy = locy * 2.f - 1.f;
        float x = ((gx + 1.f) * Wf - 1.f) * 0.5f;
        float y = ((gy + 1.f) * Hf - 1.f) * 0.5f;
        x = fminf(fmaxf(x, 0.f), Wf - 1.f);
        y = fminf(fmaxf(y, 0.f), Hf - 1.f);
        float x0f = floorf(x), y0f = floorf(y);
        float wx = x - x0f, wy = y - y0f;
        int x0 = (int)x0f, y0 = (int)y0f;
        unsigned int dx = (x0 + 1 <= W - 1) ? DD : 0;            // elems
        unsigned int dy = (y0 + 1 <= H - 1) ? (unsigned)(W * DD) : 0;
        int base = ((b * H + y0) * W + x0) * DD;

        float omx = 1.f - wx, omy = 1.f - wy;
        half4 w;
        w[0] = (_Float16)(a * omx * omy);
        w[1] = (_Float16)(a * wx  * omy);
        w[2] = (_Float16)(a * omx * wy);
        w[3] = (_Float16)(a * wx  * wy);

        dsi[(size_t)n * 16 + s] = make_int2(base, (int)((dy << 16) | dx));
        dsw[(size_t)n * 16 + s] = w;
    }
}

// ---------------- Kernel 3: sample_out v2 — fused gather + S@Wout MFMA, RELAXED REG BUDGET ----------------
// Round-8 regression diagnosed: __launch_bounds__(256,3) capped VGPR at ~85; the fused kernel's
// allocator chose 52 VGPR and serialized the 16-load gather groups (VALUBusy 57->26%, dur 2.4x).
// Fix: __launch_bounds__(256,2) -> VGPR cap 128. At <=128 VGPR the HW still runs 4 waves/SIMD
// (16 waves/CU, m69), and the gather regains its 16-loads-in-flight MLP.
// Numerics identical to round 8 (passed, absmax 0.001953125).
__global__ __launch_bounds__(256, 2) void sample_out(const ushort_t* __restrict__ mapT0,
                                                     const ushort_t* __restrict__ mapT1,
                                                     const int2* __restrict__ dsi,
                                                     const half4* __restrict__ dsw,
                                                     const ushort_t* __restrict__ WT,
                                                     const float* __restrict__ bout,
                                                     float* __restrict__ out) {
    __shared__ ushort_t slds[16][256];   // 16 rows x 256 ch bf16 (rows 8..15 zero), 8 KB
    int tid = threadIdx.x;
    int lx = tid & 63;
    int wave = tid >> 6;
    int ql = wave * 2 + (lx >> 5);                 // local query 0..7
    int nbase = blockIdx.x * 8;
    int n = nbase + ql;                            // query
    int c8 = (lx & 31) * 8;                        // channel base
    const int2*  gi = dsi + (size_t)n * 16;
    const half4* gw = dsw + (size_t)n * 16;

    int2 g[16]; half4 wh[16];
#pragma unroll
    for (int s = 0; s < 16; s++) { g[s] = gi[s]; wh[s] = gw[s]; }

    float acc[8];
#pragma unroll
    for (int i = 0; i < 8; i++) acc[i] = 0.f;

#pragma unroll
    for (int grp = 0; grp < 4; grp++) {
        const ushort_t* mp = (grp < 2) ? mapT0 : mapT1;
        uint4 u[4][4];
#pragma unroll
        for (int j = 0; j < 4; j++) {
            int s = grp * 4 + j;
            int dx = g[s].y & 0xffff;
            int dy = (int)(((unsigned int)g[s].y) >> 16);
            const ushort_t* p0 = mp + g[s].x + c8;
            u[j][0] = *(const uint4*)(p0);
            u[j][1] = *(const uint4*)(p0 + dx);
            u[j][2] = *(const uint4*)(p0 + dy);
            u[j][3] = *(const uint4*)(p0 + dx + dy);
        }
#pragma unroll
        for (int j = 0; j < 4; j++) {
            int s = grp * 4 + j;
            float w0 = (float)wh[s][0], w1 = (float)wh[s][1], w2 = (float)wh[s][2], w3 = (float)wh[s][3];
#pragma unroll
            for (int corner = 0; corner < 4; corner++) {
                uint4 v = u[j][corner];
                float wc = (corner == 0) ? w0 : (corner == 1) ? w1 : (corner == 2) ? w2 : w3;
                acc[0] += wc * h_lo(v.x); acc[1] += wc * h_hi(v.x);
                acc[2] += wc * h_lo(v.y); acc[3] += wc * h_hi(v.y);
                acc[4] += wc * h_lo(v.z); acc[5] += wc * h_hi(v.z);
                acc[6] += wc * h_lo(v.w); acc[7] += wc * h_hi(v.w);
            }
        }
    }

    // stage S row (bf16) into swizzled LDS: 16B chunk index ^= row
    ushortx8 o;
#pragma unroll
    for (int i = 0; i < 8; i++) o[i] = f2bf(acc[i]);
    {
        int chunk = (lx & 31);
        *(ushortx8*)&slds[ql][((chunk ^ ql) & 31) * 8] = o;
        // zero rows 8..15 (one ushortx8 per thread covers 8 rows x 32 chunks)
        int zr = 8 + (tid >> 5);
        ushortx8 z = {0, 0, 0, 0, 0, 0, 0, 0};
        *(ushortx8*)&slds[zr][(((tid & 31) ^ zr) & 31) * 8] = z;
    }
    __syncthreads();

    // ---- GEMM epilogue: wave 'wave' computes output cols [wave*64, wave*64+64) for rows 0..7 ----
    int mrow = lx & 15, quad = lx >> 4;
    int j0 = wave * 64;

    short8 a[8];
#pragma unroll
    for (int k = 0; k < 8; k++) {
        int chunk = (quad + 4 * k) ^ mrow;         // swizzled 16B chunk
        a[k] = *(const short8*)&slds[mrow][(chunk & 31) * 8];
    }

    floatx4 oacc[4];
#pragma unroll
    for (int nt = 0; nt < 4; nt++) oacc[nt] = {0.f, 0.f, 0.f, 0.f};

#pragma unroll
    for (int nt = 0; nt < 4; nt++) {
        const ushort_t* Wp = WT + (size_t)(j0 + nt * 16 + mrow) * DD + quad * 8;
#pragma unroll
        for (int k = 0; k < 8; k++) {
            short8 b = *(const short8*)(Wp + k * 32);
            oacc[nt] = __builtin_amdgcn_mfma_f32_16x16x32_bf16(a[k], b, oacc[nt], 0, 0, 0);
        }
    }

    // D rows = quad*4 + r (only rows 0..7 are real queries -> quads 0,1 store)
    if (quad < 2) {
        int rbase = quad * 4;
#pragma unroll
        for (int nt = 0; nt < 4; nt++) {
            float bv = bout[j0 + nt * 16 + mrow];
#pragma unroll
            for (int r = 0; r < 4; r++) {
                out[(size_t)(nbase + rbase + r) * DD + j0 + nt * 16 + mrow] = oacc[nt][r] + bv;
            }
        }
    }
}

// ---------------- launch ----------------
extern "C" void kernel_launch(void* const* d_in, const int* in_sizes, int n_in,
                              void* d_out, int out_size, void* d_ws, size_t ws_size,
                              hipStream_t stream) {
    const float* q        = (const float*)d_in[0];
    const float* map0     = (const float*)d_in[1];
    const float* map1     = (const float*)d_in[2];
    const float* base_ref = (const float*)d_in[3];
    const float* Wrd      = (const float*)d_in[4];
    const float* brd      = (const float*)d_in[5];
    const float* Woff     = (const float*)d_in[6];
    const float* boff     = (const float*)d_in[7];
    const float* Wattn    = (const float*)d_in[8];
    const float* battn    = (const float*)d_in[9];
    const float* Wout     = (const float*)d_in[10];
    const float* bout     = (const float*)d_in[11];
    float* out = (float*)d_out;

    // workspace layout (bytes) — unchanged footprint
    char* ws = (char*)d_ws;
    ushort_t*       mapT0  = (ushort_t*)(ws + 0);                // 33,554,432 (fp16)
    ushort_t*       mapT1  = (ushort_t*)(ws + 33554432);         //  8,388,608 (fp16)
    __hip_bfloat16* WoutT  = (__hip_bfloat16*)(ws + 41943040);   //    131,072 (bf16)
    float*          Wall   = (float*)(ws + 42074112);            //     65,536
    float*          bias64 = (float*)(ws + 42139648);            //        256
    int2*           dsi    = (int2*)(ws + 42139904);             //  4,194,304
    half4*          dsw    = (half4*)(ws + 46334208);            //  4,194,304

    // 1. transposes + weight pack (standalone, 16.6 KB LDS)
    prep<<<dim3(PT0 + PT1 + PTW + 64), dim3(256), 0, stream>>>(
        map0, map1, Wout, Wrd, brd, Woff, boff, Wattn, battn,
        mapT0, mapT1, WoutT, Wall, bias64);

    // 2. projections (fp32) + sampling descriptors
    proj_desc<<<dim3(BQ * QN / 64), dim3(256), 0, stream>>>(q, Wall, bias64, base_ref, dsi, dsw);

    // 3. sampling + fused output projection (MFMA epilogue, WoutT streamed from L2)
    sample_out<<<dim3(BQ * QN / 8), dim3(256), 0, stream>>>(
        mapT0, mapT1, dsi, dsw, (const ushort_t*)WoutT, bout, out);
}

// Round 10
// 245.499 us; speedup vs baseline: 1.1444x; 1.1444x over previous
//
#include <hip/hip_runtime.h>
#include <hip/hip_bf16.h>

#define BQ 4
#define QN 8192
#define DD 256
#define LL 2
#define H0c 128
#define W0c 128
#define H1c 64
#define W1c 64
#define EPSF 1e-5f

typedef unsigned short ushort_t;
typedef __attribute__((ext_vector_type(8))) short short8;
typedef __attribute__((ext_vector_type(8))) unsigned short ushortx8;
typedef __attribute__((ext_vector_type(4))) unsigned short ushortx4;
typedef __attribute__((ext_vector_type(4))) float floatx4;
typedef __attribute__((ext_vector_type(4))) _Float16 half4;

static __device__ __forceinline__ unsigned short f2bf(float f) {
    __hip_bfloat16 h = __float2bfloat16(f);
    return __builtin_bit_cast(unsigned short, h);
}
static __device__ __forceinline__ unsigned short f2h(float f) {
    _Float16 h = (_Float16)f;
    return __builtin_bit_cast(unsigned short, h);
}
// fp16 halves of a u32 -> f32 (fpext folds into v_fma_mix_f32 at the FMA site)
static __device__ __forceinline__ float h_lo(unsigned int u) {
    _Float16 h = __builtin_bit_cast(_Float16, (unsigned short)(u & 0xffffu));
    return (float)h;
}
static __device__ __forceinline__ float h_hi(unsigned int u) {
    _Float16 h = __builtin_bit_cast(_Float16, (unsigned short)(u >> 16));
    return (float)h;
}

// ---------------- Kernel 1: prep — standalone transposes + weight pack (verified, round-3/5) ----------------
// SESSION LEDGER: heterogeneous merge with proj refuted twice (r4/r6, ~97us both); keep split.
#define PT0 4096
#define PT1 1024
#define PTW 16
__global__ __launch_bounds__(256) void prep(const float* __restrict__ map0, const float* __restrict__ map1,
                                            const float* __restrict__ Wout,
                                            const float* __restrict__ Wrd, const float* __restrict__ brd,
                                            const float* __restrict__ Woff, const float* __restrict__ boff,
                                            const float* __restrict__ Wattn, const float* __restrict__ battn,
                                            ushort_t* __restrict__ mapT0, ushort_t* __restrict__ mapT1,
                                            __hip_bfloat16* __restrict__ WoutT,
                                            float* __restrict__ Wall, float* __restrict__ bias64) {
    __shared__ float tile[64][65];   // [ch_local][hw_local], 16.6 KB
    int blk = blockIdx.x;
    int tid = threadIdx.x;
    const float* in; ushort_t* outp; int HW, b, c0, hw0; bool tohalf;
    if (blk < PT0) {
        int l = blk; b = l >> 10; int r = l & 1023;
        c0 = (r >> 8) << 6; hw0 = (r & 255) << 6;
        in = map0; outp = mapT0; HW = H0c * W0c; tohalf = true;
    } else if (blk < PT0 + PT1) {
        int l = blk - PT0; b = l >> 8; int r = l & 255;
        c0 = (r >> 6) << 6; hw0 = (r & 63) << 6;
        in = map1; outp = mapT1; HW = H1c * W1c; tohalf = true;
    } else if (blk < PT0 + PT1 + PTW) {
        int l = blk - PT0 - PT1; b = 0;
        c0 = (l >> 2) << 6; hw0 = (l & 3) << 6;
        in = Wout; outp = (ushort_t*)WoutT; HW = DD; tohalf = false;
    } else {
        int l = blk - PT0 - PT1 - PTW;
        int idx = l * 256 + tid;               // 0..16383
        int k = idx >> 6, c = idx & 63;
        float v = (c < 4)  ? Wrd[k * 4 + c]
                : (c < 36) ? Woff[k * 32 + (c - 4)]
                : (c < 52) ? Wattn[k * 16 + (c - 36)]
                : 0.f;
        Wall[idx] = v;
        if (idx < 64) {
            float bv = (idx < 4)  ? brd[idx]
                     : (idx < 36) ? boff[idx - 4]
                     : (idx < 52) ? battn[idx - 36]
                     : 0.f;
            bias64[idx] = bv;
        }
        return;
    }
    const float* inb = in + (size_t)b * DD * HW + (size_t)c0 * HW + hw0;
    ushort_t* outb = outp + (size_t)b * DD * HW + (size_t)hw0 * DD + c0;

    int row = tid >> 2;             // 0..63 channel-local
    int q16 = (tid & 3) * 16;       // col base
#pragma unroll
    for (int j = 0; j < 4; j++) {
        float4 v = *(const float4*)(inb + (size_t)row * HW + q16 + j * 4);
        tile[row][q16 + j * 4 + 0] = v.x;
        tile[row][q16 + j * 4 + 1] = v.y;
        tile[row][q16 + j * 4 + 2] = v.z;
        tile[row][q16 + j * 4 + 3] = v.w;
    }
    __syncthreads();

    int hwr = tid >> 4;             // 0..15
    int c4 = (tid & 15) * 4;        // 0..60
#pragma unroll
    for (int jj = 0; jj < 4; jj++) {
        int rr = hwr + jj * 16;     // hw row 0..63
        ushortx4 o;
        if (tohalf) {
            o[0] = f2h(tile[c4 + 0][rr]);
            o[1] = f2h(tile[c4 + 1][rr]);
            o[2] = f2h(tile[c4 + 2][rr]);
            o[3] = f2h(tile[c4 + 3][rr]);
        } else {
            o[0] = f2bf(tile[c4 + 0][rr]);
            o[1] = f2bf(tile[c4 + 1][rr]);
            o[2] = f2bf(tile[c4 + 2][rr]);
            o[3] = f2bf(tile[c4 + 3][rr]);
        }
        *(ushortx4*)(outb + (size_t)rr * DD + c4) = o;
    }
}

// ---------------- Kernel 2: proj GEMM (fp32) + fused sampling-descriptor epilogue (verified) ----------------
__global__ __launch_bounds__(256) void proj_desc(const float* __restrict__ q,
                                                 const float* __restrict__ Wall,
                                                 const float* __restrict__ bias64,
                                                 const float* __restrict__ base_ref,
                                                 int2* __restrict__ dsi,
                                                 half4* __restrict__ dsw) {
    __shared__ float As[32][68];
    __shared__ float Bs[32][64];
    __shared__ float prs[64][68];
    int tid = threadIdx.x;
    int tx = tid & 15, ty = tid >> 4;
    int m0 = blockIdx.x * 64;
    float acc[4][4] = {};

    for (int kt = 0; kt < DD; kt += 32) {
#pragma unroll
        for (int j = 0; j < 8; j++) {
            int e = tid + 256 * j;
            int r = e >> 5, k = e & 31;
            As[k][r] = q[(size_t)(m0 + r) * DD + kt + k];
        }
#pragma unroll
        for (int j = 0; j < 8; j++) {
            int e = tid + 256 * j;
            int k = e >> 6, nn = e & 63;
            Bs[k][nn] = Wall[(size_t)(kt + k) * 64 + nn];
        }
        __syncthreads();
#pragma unroll
        for (int k = 0; k < 32; k++) {
            const float4 a4 = *(const float4*)&As[k][ty * 4];
            const float4 b4 = *(const float4*)&Bs[k][tx * 4];
            acc[0][0] += a4.x * b4.x; acc[0][1] += a4.x * b4.y; acc[0][2] += a4.x * b4.z; acc[0][3] += a4.x * b4.w;
            acc[1][0] += a4.y * b4.x; acc[1][1] += a4.y * b4.y; acc[1][2] += a4.y * b4.z; acc[1][3] += a4.y * b4.w;
            acc[2][0] += a4.z * b4.x; acc[2][1] += a4.z * b4.y; acc[2][2] += a4.z * b4.z; acc[2][3] += a4.z * b4.w;
            acc[3][0] += a4.w * b4.x; acc[3][1] += a4.w * b4.y; acc[3][2] += a4.w * b4.z; acc[3][3] += a4.w * b4.w;
        }
        __syncthreads();
    }

    float4 bias = *(const float4*)&bias64[tx * 4];
#pragma unroll
    for (int i = 0; i < 4; i++) {
        float4 v;
        v.x = acc[i][0] + bias.x;
        v.y = acc[i][1] + bias.y;
        v.z = acc[i][2] + bias.z;
        v.w = acc[i][3] + bias.w;
        *(float4*)&prs[ty * 4 + i][tx * 4] = v;
    }
    __syncthreads();

    int ql = tid >> 2, sq = tid & 3;
    int n = m0 + ql, b = n >> 13;        // QN = 8192
    const float* p = prs[ql];

    float mx = p[36];
#pragma unroll
    for (int i = 1; i < 16; i++) mx = fmaxf(mx, p[36 + i]);
    float sum = 0.f;
#pragma unroll
    for (int i = 0; i < 16; i++) sum += __expf(p[36 + i] - mx);
    float inv = 1.f / sum;

#pragma unroll
    for (int u = 0; u < 4; u++) {
        int s = sq * 4 + u;
        int l = s >> 3;
        float a = __expf(p[36 + s] - mx) * inv;

        int W = l ? W1c : W0c;
        int H = l ? H1c : H0c;
        float Wf = (float)W, Hf = (float)H;

        float bx = base_ref[(b * LL + l) * 2 + 0];
        float by = base_ref[(b * LL + l) * 2 + 1];
        bx = fminf(fmaxf(bx, EPSF), 1.f - EPSF);
        by = fminf(fmaxf(by, EPSF), 1.f - EPSF);
        float lgx = logf(bx / (1.f - bx));
        float lgy = logf(by / (1.f - by));
        float refx = 1.f / (1.f + __expf(-(lgx + p[l * 2 + 0])));
        float refy = 1.f / (1.f + __expf(-(lgy + p[l * 2 + 1])));

        float locx = refx + p[4 + s * 2 + 0] / Wf;
        float locy = refy + p[4 + s * 2 + 1] / Hf;
        if (l == 1) locy = locy - floorf(locy);   // jnp.remainder(y, 1.0)

        float gx = locx * 2.f - 1.f;
        float gy = locy * 2.f - 1.f;
        float x = ((gx + 1.f) * Wf - 1.f) * 0.5f;
        float y = ((gy + 1.f) * Hf - 1.f) * 0.5f;
        x = fminf(fmaxf(x, 0.f), Wf - 1.f);
        y = fminf(fmaxf(y, 0.f), Hf - 1.f);
        float x0f = floorf(x), y0f = floorf(y);
        float wx = x - x0f, wy = y - y0f;
        int x0 = (int)x0f, y0 = (int)y0f;
        unsigned int dx = (x0 + 1 <= W - 1) ? DD : 0;            // elems
        unsigned int dy = (y0 + 1 <= H - 1) ? (unsigned)(W * DD) : 0;
        int base = ((b * H + y0) * W + x0) * DD;

        float omx = 1.f - wx, omy = 1.f - wy;
        half4 w;
        w[0] = (_Float16)(a * omx * omy);
        w[1] = (_Float16)(a * wx  * omy);
        w[2] = (_Float16)(a * omx * wy);
        w[3] = (_Float16)(a * wx  * wy);

        dsi[(size_t)n * 16 + s] = make_int2(base, (int)((dy << 16) | dx));
        dsw[(size_t)n * 16 + s] = w;
    }
}

// ---------------- Kernel 3: sampling v6 — fp16 maps, mixed FMA, 8 ch/lane (verified structure) ----------------
// SESSION LEDGER: fusing the out-GEMM into this kernel refuted twice (r8/r9) — compiler picks a
// 52-VGPR schedule that serializes the 16-load gather groups regardless of launch bounds.
__global__ __launch_bounds__(256, 3) void sample_kernel(const ushort_t* __restrict__ mapT0,
                                                        const ushort_t* __restrict__ mapT1,
                                                        const int2* __restrict__ dsi,
                                                        const half4* __restrict__ dsw,
                                                        ushort_t* __restrict__ S) {
    int tid = threadIdx.x;
    int lx = tid & 63;
    int n = blockIdx.x * 8 + (tid >> 6) * 2 + (lx >> 5);   // query
    int c8 = (lx & 31) * 8;                                 // channel base
    const int2*  gi = dsi + (size_t)n * 16;
    const half4* gw = dsw + (size_t)n * 16;

    int2 g[16]; half4 wh[16];
#pragma unroll
    for (int s = 0; s < 16; s++) { g[s] = gi[s]; wh[s] = gw[s]; }

    float acc[8];
#pragma unroll
    for (int i = 0; i < 8; i++) acc[i] = 0.f;

#pragma unroll
    for (int grp = 0; grp < 4; grp++) {
        const ushort_t* mp = (grp < 2) ? mapT0 : mapT1;
        uint4 u[4][4];
#pragma unroll
        for (int j = 0; j < 4; j++) {
            int s = grp * 4 + j;
            int dx = g[s].y & 0xffff;
            int dy = (int)(((unsigned int)g[s].y) >> 16);
            const ushort_t* p0 = mp + g[s].x + c8;
            u[j][0] = *(const uint4*)(p0);
            u[j][1] = *(const uint4*)(p0 + dx);
            u[j][2] = *(const uint4*)(p0 + dy);
            u[j][3] = *(const uint4*)(p0 + dx + dy);
        }
#pragma unroll
        for (int j = 0; j < 4; j++) {
            int s = grp * 4 + j;
            float w0 = (float)wh[s][0], w1 = (float)wh[s][1], w2 = (float)wh[s][2], w3 = (float)wh[s][3];
#pragma unroll
            for (int corner = 0; corner < 4; corner++) {
                uint4 v = u[j][corner];
                float wc = (corner == 0) ? w0 : (corner == 1) ? w1 : (corner == 2) ? w2 : w3;
                acc[0] += wc * h_lo(v.x); acc[1] += wc * h_hi(v.x);
                acc[2] += wc * h_lo(v.y); acc[3] += wc * h_hi(v.y);
                acc[4] += wc * h_lo(v.z); acc[5] += wc * h_hi(v.z);
                acc[6] += wc * h_lo(v.w); acc[7] += wc * h_hi(v.w);
            }
        }
    }
    ushortx8 o;
#pragma unroll
    for (int i = 0; i < 8; i++) o[i] = f2bf(acc[i]);
    *(ushortx8*)(S + (size_t)n * DD + c8) = o;
}

// ---------------- Kernel 4: out = S(bf16) @ Wout + bout via MFMA, LDS-staged B with XOR swizzle (verified) ----------------
__global__ __launch_bounds__(256) void out_mfma(const ushort_t* __restrict__ S,
                                                const ushort_t* __restrict__ WT,
                                                const float* __restrict__ bout,
                                                float* __restrict__ out) {
    __shared__ ushort_t wlds[64][256];   // rows = n (chunk-local), cols = k; 16B chunks XOR-swizzled by row
    int tid = threadIdx.x;
    int n0c = blockIdx.x * 64;
    int wave = tid >> 6, lane = tid & 63;
    int m0 = blockIdx.y * 64 + wave * 16;
    int mrow = lane & 15, quad = lane >> 4;

#pragma unroll
    for (int i = 0; i < 8; i++) {
        int idx = tid + 256 * i;          // 0..2047
        int row = idx >> 5, c = idx & 31;
        *(uint4*)&wlds[row][(c ^ (row & 31)) * 8] =
            *(const uint4*)(WT + (size_t)(n0c + row) * DD + c * 8);
    }
    __syncthreads();

    const ushort_t* Sp = S + (size_t)(m0 + mrow) * DD + quad * 8;
    short8 a[8];
#pragma unroll
    for (int k = 0; k < 8; k++) a[k] = *(const short8*)(Sp + k * 32);

    floatx4 acc[4];
#pragma unroll
    for (int nt = 0; nt < 4; nt++) acc[nt] = {0.f, 0.f, 0.f, 0.f};

#pragma unroll
    for (int nt = 0; nt < 4; nt++) {
        int row = nt * 16 + mrow;
#pragma unroll
        for (int k = 0; k < 8; k++) {
            int c = k * 4 + quad;         // chunk index 0..31
            short8 b = *(const short8*)&wlds[row][(c ^ (row & 31)) * 8];
            acc[nt] = __builtin_amdgcn_mfma_f32_16x16x32_bf16(a[k], b, acc[nt], 0, 0, 0);
        }
    }

    int rbase = quad * 4;
#pragma unroll
    for (int nt = 0; nt < 4; nt++) {
        float bv = bout[n0c + nt * 16 + mrow];
#pragma unroll
        for (int r = 0; r < 4; r++) {
            out[(size_t)(m0 + rbase + r) * DD + n0c + nt * 16 + mrow] = acc[nt][r] + bv;
        }
    }
}

// ---------------- launch ----------------
extern "C" void kernel_launch(void* const* d_in, const int* in_sizes, int n_in,
                              void* d_out, int out_size, void* d_ws, size_t ws_size,
                              hipStream_t stream) {
    const float* q        = (const float*)d_in[0];
    const float* map0     = (const float*)d_in[1];
    const float* map1     = (const float*)d_in[2];
    const float* base_ref = (const float*)d_in[3];
    const float* Wrd      = (const float*)d_in[4];
    const float* brd      = (const float*)d_in[5];
    const float* Woff     = (const float*)d_in[6];
    const float* boff     = (const float*)d_in[7];
    const float* Wattn    = (const float*)d_in[8];
    const float* battn    = (const float*)d_in[9];
    const float* Wout     = (const float*)d_in[10];
    const float* bout     = (const float*)d_in[11];
    float* out = (float*)d_out;

    // workspace layout (bytes) — round-3 layout
    char* ws = (char*)d_ws;
    ushort_t*       mapT0  = (ushort_t*)(ws + 0);                // 33,554,432 (fp16)
    ushort_t*       mapT1  = (ushort_t*)(ws + 33554432);         //  8,388,608 (fp16)
    __hip_bfloat16* WoutT  = (__hip_bfloat16*)(ws + 41943040);   //    131,072 (bf16)
    float*          Wall   = (float*)(ws + 42074112);            //     65,536
    float*          bias64 = (float*)(ws + 42139648);            //        256
    int2*           dsi    = (int2*)(ws + 42139904);             //  4,194,304
    half4*          dsw    = (half4*)(ws + 46334208);            //  4,194,304
    ushort_t*       Sbuf   = (ushort_t*)(ws + 50528512);         // 16,777,216 (bf16)

    // 1. transposes + weight pack (standalone, 16.6 KB LDS)
    prep<<<dim3(PT0 + PT1 + PTW + 64), dim3(256), 0, stream>>>(
        map0, map1, Wout, Wrd, brd, Woff, boff, Wattn, battn,
        mapT0, mapT1, WoutT, Wall, bias64);

    // 2. projections (fp32) + sampling descriptors
    proj_desc<<<dim3(BQ * QN / 64), dim3(256), 0, stream>>>(q, Wall, bias64, base_ref, dsi, dsw);

    // 3. sampling (descriptor-driven fp16 gathers, single dispatch)
    sample_kernel<<<dim3(BQ * QN / 8), dim3(256), 0, stream>>>(
        mapT0, mapT1, dsi, dsw, Sbuf);

    // 4. output projection (bf16 MFMA, LDS-staged B)
    out_mfma<<<dim3(4, BQ * QN / 64), dim3(256), 0, stream>>>(
        Sbuf, (const ushort_t*)WoutT, bout, out);
}

// Round 12
// 245.461 us; speedup vs baseline: 1.1446x; 1.0002x over previous
//
#include <hip/hip_runtime.h>
#include <hip/hip_bf16.h>

#define BQ 4
#define QN 8192
#define DD 256
#define LL 2
#define H0c 128
#define W0c 128
#define H1c 64
#define W1c 64
#define EPSF 1e-5f

typedef unsigned short ushort_t;
typedef __attribute__((ext_vector_type(8))) short short8;
typedef __attribute__((ext_vector_type(8))) unsigned short ushortx8;
typedef __attribute__((ext_vector_type(4))) unsigned short ushortx4;
typedef __attribute__((ext_vector_type(4))) float floatx4;
typedef __attribute__((ext_vector_type(4))) _Float16 half4;

static __device__ __forceinline__ unsigned short f2bf(float f) {
    __hip_bfloat16 h = __float2bfloat16(f);
    return __builtin_bit_cast(unsigned short, h);
}
static __device__ __forceinline__ unsigned short f2h(float f) {
    _Float16 h = (_Float16)f;
    return __builtin_bit_cast(unsigned short, h);
}
// fp16 halves of a u32 -> f32 (fpext folds into v_fma_mix_f32 at the FMA site)
static __device__ __forceinline__ float h_lo(unsigned int u) {
    _Float16 h = __builtin_bit_cast(_Float16, (unsigned short)(u & 0xffffu));
    return (float)h;
}
static __device__ __forceinline__ float h_hi(unsigned int u) {
    _Float16 h = __builtin_bit_cast(_Float16, (unsigned short)(u >> 16));
    return (float)h;
}

// ---------------- Kernel 1: prep — standalone transposes + weight pack (verified) ----------------
// SESSION LEDGER: heterogeneous merge with proj refuted twice (r4/r6); sample+out fusion refuted
// twice (r8/r9). Split structure is the measured optimum.
#define PT0 4096
#define PT1 1024
#define PTW 16
__global__ __launch_bounds__(256) void prep(const float* __restrict__ map0, const float* __restrict__ map1,
                                            const float* __restrict__ Wout,
                                            const float* __restrict__ Wrd, const float* __restrict__ brd,
                                            const float* __restrict__ Woff, const float* __restrict__ boff,
                                            const float* __restrict__ Wattn, const float* __restrict__ battn,
                                            ushort_t* __restrict__ mapT0, ushort_t* __restrict__ mapT1,
                                            __hip_bfloat16* __restrict__ WoutT,
                                            float* __restrict__ Wall, float* __restrict__ bias64) {
    __shared__ float tile[64][65];   // [ch_local][hw_local], 16.6 KB
    int blk = blockIdx.x;
    int tid = threadIdx.x;
    const float* in; ushort_t* outp; int HW, b, c0, hw0; bool tohalf;
    if (blk < PT0) {
        int l = blk; b = l >> 10; int r = l & 1023;
        c0 = (r >> 8) << 6; hw0 = (r & 255) << 6;
        in = map0; outp = mapT0; HW = H0c * W0c; tohalf = true;
    } else if (blk < PT0 + PT1) {
        int l = blk - PT0; b = l >> 8; int r = l & 255;
        c0 = (r >> 6) << 6; hw0 = (r & 63) << 6;
        in = map1; outp = mapT1; HW = H1c * W1c; tohalf = true;
    } else if (blk < PT0 + PT1 + PTW) {
        int l = blk - PT0 - PT1; b = 0;
        c0 = (l >> 2) << 6; hw0 = (l & 3) << 6;
        in = Wout; outp = (ushort_t*)WoutT; HW = DD; tohalf = false;
    } else {
        int l = blk - PT0 - PT1 - PTW;
        int idx = l * 256 + tid;               // 0..16383
        int k = idx >> 6, c = idx & 63;
        float v = (c < 4)  ? Wrd[k * 4 + c]
                : (c < 36) ? Woff[k * 32 + (c - 4)]
                : (c < 52) ? Wattn[k * 16 + (c - 36)]
                : 0.f;
        Wall[idx] = v;
        if (idx < 64) {
            float bv = (idx < 4)  ? brd[idx]
                     : (idx < 36) ? boff[idx - 4]
                     : (idx < 52) ? battn[idx - 36]
                     : 0.f;
            bias64[idx] = bv;
        }
        return;
    }
    const float* inb = in + (size_t)b * DD * HW + (size_t)c0 * HW + hw0;
    ushort_t* outb = outp + (size_t)b * DD * HW + (size_t)hw0 * DD + c0;

    int row = tid >> 2;             // 0..63 channel-local
    int q16 = (tid & 3) * 16;       // col base
#pragma unroll
    for (int j = 0; j < 4; j++) {
        float4 v = *(const float4*)(inb + (size_t)row * HW + q16 + j * 4);
        tile[row][q16 + j * 4 + 0] = v.x;
        tile[row][q16 + j * 4 + 1] = v.y;
        tile[row][q16 + j * 4 + 2] = v.z;
        tile[row][q16 + j * 4 + 3] = v.w;
    }
    __syncthreads();

    int hwr = tid >> 4;             // 0..15
    int c4 = (tid & 15) * 4;        // 0..60
#pragma unroll
    for (int jj = 0; jj < 4; jj++) {
        int rr = hwr + jj * 16;     // hw row 0..63
        ushortx4 o;
        if (tohalf) {
            o[0] = f2h(tile[c4 + 0][rr]);
            o[1] = f2h(tile[c4 + 1][rr]);
            o[2] = f2h(tile[c4 + 2][rr]);
            o[3] = f2h(tile[c4 + 3][rr]);
        } else {
            o[0] = f2bf(tile[c4 + 0][rr]);
            o[1] = f2bf(tile[c4 + 1][rr]);
            o[2] = f2bf(tile[c4 + 2][rr]);
            o[3] = f2bf(tile[c4 + 3][rr]);
        }
        *(ushortx4*)(outb + (size_t)rr * DD + c4) = o;
    }
}

// ---------------- Kernel 2: proj GEMM (fp32) + fused sampling-descriptor epilogue (verified) ----------------
__global__ __launch_bounds__(256) void proj_desc(const float* __restrict__ q,
                                                 const float* __restrict__ Wall,
                                                 const float* __restrict__ bias64,
                                                 const float* __restrict__ base_ref,
                                                 int2* __restrict__ dsi,
                                                 half4* __restrict__ dsw) {
    __shared__ float As[32][68];
    __shared__ float Bs[32][64];
    __shared__ float prs[64][68];
    int tid = threadIdx.x;
    int tx = tid & 15, ty = tid >> 4;
    int m0 = blockIdx.x * 64;
    float acc[4][4] = {};

    for (int kt = 0; kt < DD; kt += 32) {
#pragma unroll
        for (int j = 0; j < 8; j++) {
            int e = tid + 256 * j;
            int r = e >> 5, k = e & 31;
            As[k][r] = q[(size_t)(m0 + r) * DD + kt + k];
        }
#pragma unroll
        for (int j = 0; j < 8; j++) {
            int e = tid + 256 * j;
            int k = e >> 6, nn = e & 63;
            Bs[k][nn] = Wall[(size_t)(kt + k) * 64 + nn];
        }
        __syncthreads();
#pragma unroll
        for (int k = 0; k < 32; k++) {
            const float4 a4 = *(const float4*)&As[k][ty * 4];
            const float4 b4 = *(const float4*)&Bs[k][tx * 4];
            acc[0][0] += a4.x * b4.x; acc[0][1] += a4.x * b4.y; acc[0][2] += a4.x * b4.z; acc[0][3] += a4.x * b4.w;
            acc[1][0] += a4.y * b4.x; acc[1][1] += a4.y * b4.y; acc[1][2] += a4.y * b4.z; acc[1][3] += a4.y * b4.w;
            acc[2][0] += a4.z * b4.x; acc[2][1] += a4.z * b4.y; acc[2][2] += a4.z * b4.z; acc[2][3] += a4.z * b4.w;
            acc[3][0] += a4.w * b4.x; acc[3][1] += a4.w * b4.y; acc[3][2] += a4.w * b4.z; acc[3][3] += a4.w * b4.w;
        }
        __syncthreads();
    }

    float4 bias = *(const float4*)&bias64[tx * 4];
#pragma unroll
    for (int i = 0; i < 4; i++) {
        float4 v;
        v.x = acc[i][0] + bias.x;
        v.y = acc[i][1] + bias.y;
        v.z = acc[i][2] + bias.z;
        v.w = acc[i][3] + bias.w;
        *(float4*)&prs[ty * 4 + i][tx * 4] = v;
    }
    __syncthreads();

    int ql = tid >> 2, sq = tid & 3;
    int n = m0 + ql, b = n >> 13;        // QN = 8192
    const float* p = prs[ql];

    float mx = p[36];
#pragma unroll
    for (int i = 1; i < 16; i++) mx = fmaxf(mx, p[36 + i]);
    float sum = 0.f;
#pragma unroll
    for (int i = 0; i < 16; i++) sum += __expf(p[36 + i] - mx);
    float inv = 1.f / sum;

#pragma unroll
    for (int u = 0; u < 4; u++) {
        int s = sq * 4 + u;
        int l = s >> 3;
        float a = __expf(p[36 + s] - mx) * inv;

        int W = l ? W1c : W0c;
        int H = l ? H1c : H0c;
        float Wf = (float)W, Hf = (float)H;

        float bx = base_ref[(b * LL + l) * 2 + 0];
        float by = base_ref[(b * LL + l) * 2 + 1];
        bx = fminf(fmaxf(bx, EPSF), 1.f - EPSF);
        by = fminf(fmaxf(by, EPSF), 1.f - EPSF);
        float lgx = logf(bx / (1.f - bx));
        float lgy = logf(by / (1.f - by));
        float refx = 1.f / (1.f + __expf(-(lgx + p[l * 2 + 0])));
        float refy = 1.f / (1.f + __expf(-(lgy + p[l * 2 + 1])));

        float locx = refx + p[4 + s * 2 + 0] / Wf;
        float locy = refy + p[4 + s * 2 + 1] / Hf;
        if (l == 1) locy = locy - floorf(locy);   // jnp.remainder(y, 1.0)

        float gx = locx * 2.f - 1.f;
        float gy = locy * 2.f - 1.f;
        float x = ((gx + 1.f) * Wf - 1.f) * 0.5f;
        float y = ((gy + 1.f) * Hf - 1.f) * 0.5f;
        x = fminf(fmaxf(x, 0.f), Wf - 1.f);
        y = fminf(fmaxf(y, 0.f), Hf - 1.f);
        float x0f = floorf(x), y0f = floorf(y);
        float wx = x - x0f, wy = y - y0f;
        int x0 = (int)x0f, y0 = (int)y0f;
        unsigned int dx = (x0 + 1 <= W - 1) ? DD : 0;            // elems
        unsigned int dy = (y0 + 1 <= H - 1) ? (unsigned)(W * DD) : 0;
        int base = ((b * H + y0) * W + x0) * DD;

        float omx = 1.f - wx, omy = 1.f - wy;
        half4 w;
        w[0] = (_Float16)(a * omx * omy);
        w[1] = (_Float16)(a * wx  * omy);
        w[2] = (_Float16)(a * omx * wy);
        w[3] = (_Float16)(a * wx  * wy);

        dsi[(size_t)n * 16 + s] = make_int2(base, (int)((dy << 16) | dx));
        dsw[(size_t)n * 16 + s] = w;
    }
}

// ---------------- Kernel 3: sampling v6 — fp16 maps, mixed FMA, 8 ch/lane (verified) ----------------
__global__ __launch_bounds__(256, 3) void sample_kernel(const ushort_t* __restrict__ mapT0,
                                                        const ushort_t* __restrict__ mapT1,
                                                        const int2* __restrict__ dsi,
                                                        const half4* __restrict__ dsw,
                                                        ushort_t* __restrict__ S) {
    int tid = threadIdx.x;
    int lx = tid & 63;
    int n = blockIdx.x * 8 + (tid >> 6) * 2 + (lx >> 5);   // query
    int c8 = (lx & 31) * 8;                                 // channel base
    const int2*  gi = dsi + (size_t)n * 16;
    const half4* gw = dsw + (size_t)n * 16;

    int2 g[16]; half4 wh[16];
#pragma unroll
    for (int s = 0; s < 16; s++) { g[s] = gi[s]; wh[s] = gw[s]; }

    float acc[8];
#pragma unroll
    for (int i = 0; i < 8; i++) acc[i] = 0.f;

#pragma unroll
    for (int grp = 0; grp < 4; grp++) {
        const ushort_t* mp = (grp < 2) ? mapT0 : mapT1;
        uint4 u[4][4];
#pragma unroll
        for (int j = 0; j < 4; j++) {
            int s = grp * 4 + j;
            int dx = g[s].y & 0xffff;
            int dy = (int)(((unsigned int)g[s].y) >> 16);
            const ushort_t* p0 = mp + g[s].x + c8;
            u[j][0] = *(const uint4*)(p0);
            u[j][1] = *(const uint4*)(p0 + dx);
            u[j][2] = *(const uint4*)(p0 + dy);
            u[j][3] = *(const uint4*)(p0 + dx + dy);
        }
#pragma unroll
        for (int j = 0; j < 4; j++) {
            int s = grp * 4 + j;
            float w0 = (float)wh[s][0], w1 = (float)wh[s][1], w2 = (float)wh[s][2], w3 = (float)wh[s][3];
#pragma unroll
            for (int corner = 0; corner < 4; corner++) {
                uint4 v = u[j][corner];
                float wc = (corner == 0) ? w0 : (corner == 1) ? w1 : (corner == 2) ? w2 : w3;
                acc[0] += wc * h_lo(v.x); acc[1] += wc * h_hi(v.x);
                acc[2] += wc * h_lo(v.y); acc[3] += wc * h_hi(v.y);
                acc[4] += wc * h_lo(v.z); acc[5] += wc * h_hi(v.z);
                acc[6] += wc * h_lo(v.w); acc[7] += wc * h_hi(v.w);
            }
        }
    }
    ushortx8 o;
#pragma unroll
    for (int i = 0; i < 8; i++) o[i] = f2bf(acc[i]);
    *(ushortx8*)(S + (size_t)n * DD + c8) = o;
}

// ---------------- Kernel 4: out_mfma v2 — one block per 64-row m-tile, n-chunk loop ----------------
// v1 (grid 4x512) read S 4x (67 MB) and staged WT 2048x. v2: grid 512; a-frags (S) hoisted and
// read ONCE; loop nc=0..3 stages WT rows [nc*64, nc*64+64) into the same 32 KB LDS and computes
// that 64-col chunk. Same MFMA shape/k-order/swizzle/bias => bit-identical output to v1.
__global__ __launch_bounds__(256) void out_mfma(const ushort_t* __restrict__ S,
                                                const ushort_t* __restrict__ WT,
                                                const float* __restrict__ bout,
                                                float* __restrict__ out) {
    __shared__ ushort_t wlds[64][256];   // 32 KB: n-chunk rows x k; 16B chunks XOR-swizzled by row
    int tid = threadIdx.x;
    int wave = tid >> 6, lane = tid & 63;
    int m0 = blockIdx.x * 64 + wave * 16;
    int mrow = lane & 15, quad = lane >> 4;

    // hoisted: each wave's A fragments (16 rows x K=256) — S read exactly once per element
    const ushort_t* Sp = S + (size_t)(m0 + mrow) * DD + quad * 8;
    short8 a[8];
#pragma unroll
    for (int k = 0; k < 8; k++) a[k] = *(const short8*)(Sp + k * 32);

    for (int nc = 0; nc < 4; nc++) {
        __syncthreads();   // previous chunk's LDS reads complete before overwrite (no-op at nc=0)
#pragma unroll
        for (int i = 0; i < 8; i++) {
            int idx = tid + 256 * i;          // 0..2047
            int row = idx >> 5, c = idx & 31;
            *(uint4*)&wlds[row][(c ^ (row & 31)) * 8] =
                *(const uint4*)(WT + (size_t)(nc * 64 + row) * DD + c * 8);
        }
        __syncthreads();

        floatx4 acc[4];
#pragma unroll
        for (int nt = 0; nt < 4; nt++) acc[nt] = {0.f, 0.f, 0.f, 0.f};

#pragma unroll
        for (int nt = 0; nt < 4; nt++) {
            int row = nt * 16 + mrow;
#pragma unroll
            for (int k = 0; k < 8; k++) {
                int c = k * 4 + quad;         // chunk index 0..31
                short8 b = *(const short8*)&wlds[row][(c ^ (row & 31)) * 8];
                acc[nt] = __builtin_amdgcn_mfma_f32_16x16x32_bf16(a[k], b, acc[nt], 0, 0, 0);
            }
        }

        int rbase = quad * 4;
#pragma unroll
        for (int nt = 0; nt < 4; nt++) {
            float bv = bout[nc * 64 + nt * 16 + mrow];
#pragma unroll
            for (int r = 0; r < 4; r++) {
                out[(size_t)(m0 + rbase + r) * DD + nc * 64 + nt * 16 + mrow] = acc[nt][r] + bv;
            }
        }
    }
}

// ---------------- launch ----------------
extern "C" void kernel_launch(void* const* d_in, const int* in_sizes, int n_in,
                              void* d_out, int out_size, void* d_ws, size_t ws_size,
                              hipStream_t stream) {
    const float* q        = (const float*)d_in[0];
    const float* map0     = (const float*)d_in[1];
    const float* map1     = (const float*)d_in[2];
    const float* base_ref = (const float*)d_in[3];
    const float* Wrd      = (const float*)d_in[4];
    const float* brd      = (const float*)d_in[5];
    const float* Woff     = (const float*)d_in[6];
    const float* boff     = (const float*)d_in[7];
    const float* Wattn    = (const float*)d_in[8];
    const float* battn    = (const float*)d_in[9];
    const float* Wout     = (const float*)d_in[10];
    const float* bout     = (const float*)d_in[11];
    float* out = (float*)d_out;

    // workspace layout (bytes) — unchanged
    char* ws = (char*)d_ws;
    ushort_t*       mapT0  = (ushort_t*)(ws + 0);                // 33,554,432 (fp16)
    ushort_t*       mapT1  = (ushort_t*)(ws + 33554432);         //  8,388,608 (fp16)
    __hip_bfloat16* WoutT  = (__hip_bfloat16*)(ws + 41943040);   //    131,072 (bf16)
    float*          Wall   = (float*)(ws + 42074112);            //     65,536
    float*          bias64 = (float*)(ws + 42139648);            //        256
    int2*           dsi    = (int2*)(ws + 42139904);             //  4,194,304
    half4*          dsw    = (half4*)(ws + 46334208);            //  4,194,304
    ushort_t*       Sbuf   = (ushort_t*)(ws + 50528512);         // 16,777,216 (bf16)

    // 1. transposes + weight pack (standalone, 16.6 KB LDS)
    prep<<<dim3(PT0 + PT1 + PTW + 64), dim3(256), 0, stream>>>(
        map0, map1, Wout, Wrd, brd, Woff, boff, Wattn, battn,
        mapT0, mapT1, WoutT, Wall, bias64);

    // 2. projections (fp32) + sampling descriptors
    proj_desc<<<dim3(BQ * QN / 64), dim3(256), 0, stream>>>(q, Wall, bias64, base_ref, dsi, dsw);

    // 3. sampling (descriptor-driven fp16 gathers, single dispatch)
    sample_kernel<<<dim3(BQ * QN / 8), dim3(256), 0, stream>>>(
        mapT0, mapT1, dsi, dsw, Sbuf);

    // 4. output projection (bf16 MFMA, S read once, WT n-chunk loop)
    out_mfma<<<dim3(BQ * QN / 64), dim3(256), 0, stream>>>(
        Sbuf, (const ushort_t*)WoutT, bout, out);
}